// Round 5
// baseline (643.202 us; speedup 1.0000x reference)
//
#include <hip/hip_runtime.h>
#include <stdint.h>

#define NN 8192
#define DIM 256
#define NSPEC 32
#define ZSPLIT 32
#define MCH (NN / ZSPLIT)   // 256 m-rows per block
#define ETA 0.5f
#define COEFF 0.125f      // D/(N*EPS^2) = 256/(8192*0.25)
#define LNEPS 1e-5f

// ---------------- gemm_ATW: P[n][z][s] = partial of OUT = A^T @ W ---------------------------
// OUT[n,s] = sum_m A[m,n] * W[m,s].  Pure f32 VALU: this GEMM is memory-bound (16 FLOP/B),
// so MFMA/bf16/transpose buy nothing — stream A row-major with 1KB-contiguous float4 loads.
// Block: 256 thr = 4 waves; wave w owns s-octet w*8..w*8+7; lane l owns n = n0+l*4..+3.
// W-chunk (256 x 32 f32 = 32 KB) staged in LDS; broadcast ds_reads (uniform addr, no conflict).
__launch_bounds__(256, 4)
__global__ void gemm_ATW(const float* __restrict__ A, const float* __restrict__ W,
                         float* __restrict__ P) {
    __shared__ float ldsW[MCH * NSPEC];   // 32 KB
    const int t = threadIdx.x;
    const int w = t >> 6, l = t & 63;
    const long n0 = (long)blockIdx.x * 256;
    const int  m0 = blockIdx.y * MCH;

#pragma unroll
    for (int i = 0; i < 8; ++i) {
        int idx = i * 256 + t;            // 2048 float4s = 256 rows x 32 s
        *(float4*)&ldsW[idx * 4] = *(const float4*)&W[(long)m0 * NSPEC + idx * 4];
    }
    __syncthreads();

    float acc[4][8];
#pragma unroll
    for (int j = 0; j < 4; ++j)
#pragma unroll
        for (int k = 0; k < 8; ++k) acc[j][k] = 0.f;

    const float* Arow = A + (long)m0 * NN + n0 + l * 4;
    const float* wrow = ldsW + w * 8;
#pragma unroll 4
    for (int im = 0; im < MCH; ++im) {
        float4 a4 = *(const float4*)(Arow + (long)im * NN);
        float4 w0 = *(const float4*)(wrow + im * NSPEC);
        float4 w1 = *(const float4*)(wrow + im * NSPEC + 4);
        float a[4]  = {a4.x, a4.y, a4.z, a4.w};
        float ww[8] = {w0.x, w0.y, w0.z, w0.w, w1.x, w1.y, w1.z, w1.w};
#pragma unroll
        for (int j = 0; j < 4; ++j)
#pragma unroll
            for (int k = 0; k < 8; ++k)
                acc[j][k] += a[j] * ww[k];
    }

    // P layout [n][z][s]: reducer reads each n's 32x32 block fully contiguous (no pow2 camping)
    float* Pp = P + ((n0 + l * 4) * ZSPLIT + blockIdx.y) * NSPEC + w * 8;
#pragma unroll
    for (int j = 0; j < 4; ++j) {
        float4 o0 = {acc[j][0], acc[j][1], acc[j][2], acc[j][3]};
        float4 o1 = {acc[j][4], acc[j][5], acc[j][6], acc[j][7]};
        *(float4*)&Pp[(long)j * ZSPLIT * NSPEC] = o0;
        *(float4*)&Pp[(long)j * ZSPLIT * NSPEC + 4] = o1;
    }
}

// ---------------- reduce32: Wf[n,s] = sum_z P[n][z][s] --------------------------------------
__global__ void reduce32(const float* __restrict__ P, float* __restrict__ Wf) {
    int t = threadIdx.x;
    long n = (long)blockIdx.x * 8 + (t >> 5);
    int s = t & 31;
    const float* p = P + n * (ZSPLIT * NSPEC) + s;
    float v = 0.f;
#pragma unroll
    for (int z = 0; z < ZSPLIT; ++z) v += p[z * NSPEC];
    Wf[n * NSPEC + s] = v;
}

// ---------------- Phi[k,s,d] = sum_n W_k[n,s] * H[n,d]  (f32, atomic split over n) -----------
__global__ void phi_kernel(const float* __restrict__ W0, const float* __restrict__ W1,
                           const float* __restrict__ W2, const float* __restrict__ W3,
                           const float* __restrict__ H, float* __restrict__ Phi) {
    __shared__ float ldsW[64 * NSPEC];   // 8 KB
    int t = threadIdx.x;
    int s0 = (t >> 6) * 8;
    int d0 = (t & 63) * 4;
    int n0 = blockIdx.x * 128;
    int k = blockIdx.y;
    const float* W = (k == 0) ? W0 : (k == 1) ? W1 : (k == 2) ? W2 : W3;
    float4 acc[8];
#pragma unroll
    for (int j = 0; j < 8; ++j) acc[j] = (float4){0.f, 0.f, 0.f, 0.f};

    for (int tile = 0; tile < 2; ++tile) {
        int nb = n0 + tile * 64;
#pragma unroll
        for (int i = 0; i < 8; ++i) {
            int idx = i * 256 + t;
            ldsW[idx] = W[(long)(nb + (idx >> 5)) * NSPEC + (idx & 31)];
        }
        __syncthreads();
        for (int nn = 0; nn < 64; ++nn) {
            float4 x = *(const float4*)&H[(long)(nb + nn) * DIM + d0];
#pragma unroll
            for (int j = 0; j < 8; ++j) {
                float vs = ldsW[nn * NSPEC + s0 + j];
                acc[j].x += vs * x.x; acc[j].y += vs * x.y;
                acc[j].z += vs * x.z; acc[j].w += vs * x.w;
            }
        }
        __syncthreads();
    }
#pragma unroll
    for (int j = 0; j < 8; ++j) {
        float* ph = &Phi[((k * NSPEC) + s0 + j) * DIM + d0];
        atomicAdd(ph + 0, acc[j].x);
        atomicAdd(ph + 1, acc[j].y);
        atomicAdd(ph + 2, acc[j].z);
        atomicAdd(ph + 3, acc[j].w);
    }
}

// ---------------- Tc[s,d] = spec_w*sum_k hw*q - lap*eig*sum_k hw*phi; + tail outputs ---------
__global__ void tc_kernel(const float* __restrict__ Phi,
                          const float* __restrict__ eigvals,
                          const float* __restrict__ spec_logits,
                          const float* __restrict__ lap_logits,
                          const float* __restrict__ hop_weights,
                          float* __restrict__ Tc,
                          float* __restrict__ out_tail) {
    int s = blockIdx.x, t = threadIdx.x;
    float hw0 = hop_weights[0], hw1 = hop_weights[1], hw2 = hop_weights[2], hw3 = hop_weights[3];
    float hm = fmaxf(fmaxf(hw0, hw1), fmaxf(hw2, hw3));
    hw0 = expf(hw0 - hm); hw1 = expf(hw1 - hm); hw2 = expf(hw2 - hm); hw3 = expf(hw3 - hm);
    float hs = hw0 + hw1 + hw2 + hw3;
    hw0 /= hs; hw1 /= hs; hw2 /= hs; hw3 /= hs;
    float hw[4] = {hw0, hw1, hw2, hw3};
    float sm = -1e30f;
    for (int j = 0; j < NSPEC; ++j) sm = fmaxf(sm, spec_logits[j]);
    float ssum = 0.f;
    for (int j = 0; j < NSPEC; ++j) ssum += expf(spec_logits[j] - sm);
    float spec_w_s = expf(spec_logits[s] - sm) / ssum;
    float lp = lap_logits[s];
    float lap = (lp > 20.f) ? lp : log1pf(expf(lp));
    float le = lap * eigvals[s];

    __shared__ float red[4];
    float accR = 0.f, accL = 0.f;
    for (int k = 0; k < 4; ++k) {
        float phi = Phi[(k * NSPEC + s) * DIM + t];
        float v = phi * phi;
        for (int off = 32; off; off >>= 1) v += __shfl_xor(v, off);
        if ((t & 63) == 0) red[t >> 6] = v;
        __syncthreads();
        float ssq = red[0] + red[1] + red[2] + red[3];
        __syncthreads();
        float q = COEFF * phi / (1.f + COEFF * ssq);   // Sherman-Morrison: solve(I+c*pp^T, p)
        accR += hw[k] * q;
        accL += hw[k] * phi;
    }
    Tc[s * DIM + t] = spec_w_s * accR - le * accL;
    if (s == 0) {
        if (t < 4) out_tail[t] = hw[t];
        if (t < NSPEC) out_tail[4 + t] = expf(spec_logits[t] - sm) / ssum;
    }
}

// ---------------- final: G=V@Tc, H_half=H+ETA*G, soft-threshold, LayerNorm ----------------
__launch_bounds__(256)
__global__ void final_kernel(const float* __restrict__ H, const float* __restrict__ V,
                             const float* __restrict__ Tc, const float* __restrict__ thr,
                             const float* __restrict__ gamma, const float* __restrict__ beta,
                             float* __restrict__ out) {
    __shared__ float tc[NSPEC * DIM];   // 32 KB
    int t = threadIdx.x;
    {
        const float4* s4 = (const float4*)Tc;
        float4* d4 = (float4*)tc;
        for (int i = 0; i < 8; ++i) d4[i * 256 + t] = s4[i * 256 + t];
    }
    __syncthreads();
    int w = t >> 6, l = t & 63;
    long row = (long)blockIdx.x * 4 + w;
    int d0 = l * 4;
    const float* vrow = V + row * NSPEC;
    float4 G = {0.f, 0.f, 0.f, 0.f};
#pragma unroll 8
    for (int s = 0; s < NSPEC; ++s) {
        float vs = vrow[s];
        float4 c4 = *(const float4*)&tc[s * DIM + d0];
        G.x += vs * c4.x; G.y += vs * c4.y; G.z += vs * c4.z; G.w += vs * c4.w;
    }
    float4 h = *(const float4*)&H[row * DIM + d0];
    float4 th = *(const float4*)&thr[d0];
    float y[4];
    y[0] = h.x + ETA * G.x; y[1] = h.y + ETA * G.y;
    y[2] = h.z + ETA * G.z; y[3] = h.w + ETA * G.w;
    float tv[4] = {th.x, th.y, th.z, th.w};
    float s1 = 0.f, s2 = 0.f;
#pragma unroll
    for (int j = 0; j < 4; ++j) {
        float a = fabsf(y[j]) - tv[j];
        y[j] = (a > 0.f) ? copysignf(a, y[j]) : 0.f;
        s1 += y[j];
        s2 += y[j] * y[j];
    }
    for (int off = 32; off; off >>= 1) { s1 += __shfl_xor(s1, off); s2 += __shfl_xor(s2, off); }
    float mean = s1 * (1.f / DIM);
    float var = s2 * (1.f / DIM) - mean * mean;
    float inv = rsqrtf(var + LNEPS);
    float4 g4 = *(const float4*)&gamma[d0];
    float4 b4 = *(const float4*)&beta[d0];
    float4 o;
    o.x = (y[0] - mean) * inv * g4.x + b4.x;
    o.y = (y[1] - mean) * inv * g4.y + b4.y;
    o.z = (y[2] - mean) * inv * g4.z + b4.z;
    o.w = (y[3] - mean) * inv * g4.w + b4.w;
    *(float4*)&out[row * DIM + d0] = o;
}

extern "C" void kernel_launch(void* const* d_in, const int* in_sizes, int n_in,
                              void* d_out, int out_size, void* d_ws, size_t ws_size,
                              hipStream_t stream) {
    const float* H = (const float*)d_in[0];
    const float* A = (const float*)d_in[1];
    const float* V = (const float*)d_in[2];
    const float* eigvals = (const float*)d_in[3];
    const float* spec_logits = (const float*)d_in[4];
    const float* lap_logits = (const float*)d_in[5];
    const float* hop_weights = (const float*)d_in[6];
    const float* threshold = (const float*)d_in[7];
    const float* ln_gamma = (const float*)d_in[8];
    const float* ln_beta = (const float*)d_in[9];

    char* ws = (char*)d_ws;
    float* P   = (float*)ws;                        // NN*ZSPLIT*NSPEC*4 = 32 MB split-K partials
    float* W1f = (float*)(ws + 33554432);           // 1 MB
    float* W2f = (float*)(ws + 34603008);           // 1 MB
    float* W3f = (float*)(ws + 35651584);           // 1 MB
    float* Phi = (float*)(ws + 36700160);           // 128 KB
    float* Tc  = (float*)(ws + 36831232);           // 32 KB
    float* out = (float*)d_out;

    hipMemsetAsync(Phi, 0, 4 * NSPEC * DIM * sizeof(float), stream);

    gemm_ATW<<<dim3(32, ZSPLIT), 256, 0, stream>>>(A, V, P);
    reduce32<<<1024, 256, 0, stream>>>(P, W1f);
    gemm_ATW<<<dim3(32, ZSPLIT), 256, 0, stream>>>(A, W1f, P);
    reduce32<<<1024, 256, 0, stream>>>(P, W2f);
    gemm_ATW<<<dim3(32, ZSPLIT), 256, 0, stream>>>(A, W2f, P);
    reduce32<<<1024, 256, 0, stream>>>(P, W3f);

    phi_kernel<<<dim3(64, 4), 256, 0, stream>>>(V, W1f, W2f, W3f, H, Phi);
    tc_kernel<<<NSPEC, 256, 0, stream>>>(Phi, eigvals, spec_logits, lap_logits, hop_weights,
                                         Tc, out + (long)NN * DIM);
    final_kernel<<<2048, 256, 0, stream>>>(H, V, Tc, threshold, ln_gamma, ln_beta, out);
}

// Round 6
// 593.029 us; speedup vs baseline: 1.0846x; 1.0846x over previous
//
#include <hip/hip_runtime.h>
#include <hip/hip_bf16.h>
#include <stdint.h>

#define NN 8192
#define LDAT 8320          // padded ATbf row stride (elements): 16640 B = 130*128B, channel-rotating
#define DIM 256
#define NSPEC 32
#define ZS 32              // split-K factor for hop GEMM
#define KC (NN / ZS)       // 256 k per z-chunk
#define NKS (KC / 32)      // 8 MFMA K-steps per chunk
#define PZSTRIDE (NN * NSPEC + 256)   // padded z-plane stride (floats): channel-rotating
#define ETA 0.5f
#define COEFF 0.125f       // D/(N*EPS^2) = 256/(8192*0.25)
#define LNEPS 1e-5f

typedef __attribute__((ext_vector_type(8))) short bf16x8;
typedef __attribute__((ext_vector_type(4))) float f32x4;
typedef __attribute__((ext_vector_type(4))) unsigned short u16x4;

__device__ __forceinline__ unsigned short bf2u(__hip_bfloat16 b) {
    union { __hip_bfloat16 b; unsigned short u; } c; c.b = b; return c.u;
}

// ---------------- cast + transpose A: f32 (8192x8192) -> bf16 AT[n,m] = A[m,n], stride LDAT ---
// (round-2 version: diagonal block remap, swizzled LDS, padded channel-rotating writes)
__global__ void castT_A(const float* __restrict__ A, __hip_bfloat16* __restrict__ AT) {
    __shared__ unsigned short lds[64 * 72];
    const int t = threadIdx.x;
    const long r0 = (long)blockIdx.x * 64;
    const long c0 = (long)((blockIdx.x + blockIdx.y) & 127) * 64;   // diagonal remap
    const int rg = t >> 4;          // 0..15: 4-row granule of A
    const int cg = t & 15;          // 0..15: 4-col group of A

    float4 a[4];
#pragma unroll
    for (int i = 0; i < 4; ++i)
        a[i] = *(const float4*)&A[(r0 + rg * 4 + i) * NN + c0 + cg * 4];

#pragma unroll
    for (int j = 0; j < 4; ++j) {
        u16x4 col;
        col[0] = bf2u(__float2bfloat16(((const float*)&a[0])[j]));
        col[1] = bf2u(__float2bfloat16(((const float*)&a[1])[j]));
        col[2] = bf2u(__float2bfloat16(((const float*)&a[2])[j]));
        col[3] = bf2u(__float2bfloat16(((const float*)&a[3])[j]));
        int c = cg * 4 + j;
        int s = (((rg >> 1) + cg) & 7) * 2 + (rg & 1);
        *(u16x4*)&lds[c * 72 + s * 4] = col;
    }
    __syncthreads();

#pragma unroll
    for (int i = 0; i < 2; ++i) {
        int idx = i * 256 + t;
        int c = idx >> 3, g = idx & 7;
        int s8 = (g + (c >> 2)) & 7;
        bf16x8 v = *(const bf16x8*)&lds[c * 72 + s8 * 8];
        *(bf16x8*)&AT[(c0 + c) * LDAT + r0 + g * 8] = v;
    }
}

// ---------------- transpose+cast V: f32 (8192x32) -> bf16 VT (32x8192) ----------------
__global__ void trans_V(const float* __restrict__ V, __hip_bfloat16* __restrict__ VT) {
    __shared__ float tile[64 * 33];
    int n0 = blockIdx.x * 64;
    int t = threadIdx.x;
    for (int i = 0; i < 8; ++i) {
        int idx = i * 256 + t;
        tile[(idx >> 5) * 33 + (idx & 31)] = V[(long)(n0 + (idx >> 5)) * NSPEC + (idx & 31)];
    }
    __syncthreads();
    for (int i = 0; i < 8; ++i) {
        int idx = i * 256 + t;
        int s = idx >> 6, r = idx & 63;
        VT[(long)s * NN + n0 + r] = __float2bfloat16(tile[r * 33 + s]);
    }
}

// ---------------- hop GEMM, register-direct MFMA (no LDS, no barriers) ----------------------
// P_z[n,s] = sum_{k in z-chunk} AT[n,k] * WT[s,k].  A-frags and B-frags loaded straight
// global->VGPR (16 B/lane dwordx4); register double-buffer + full unroll keeps ~12 loads
// in flight per wave with compiler-counted vmcnt — no syncthreads drain (the round<=4
// structure was latency-bound: every K-step drained vmcnt(0) at the barrier).
// Wave: 64 n-rows x 32 s. Block: 4 waves = 256 n. Grid (32, ZS).
__launch_bounds__(256, 4)
__global__ void gemm_mfma(const __hip_bfloat16* __restrict__ AT,
                          const __hip_bfloat16* __restrict__ WT,
                          float* __restrict__ P) {
    const int t = threadIdx.x;
    const int wv = t >> 6, l = t & 63;
    const long n0 = (long)blockIdx.x * 256 + wv * 64;
    const long kb = (long)blockIdx.y * KC;
    const int lr = l & 15;            // frag row (n within 16-tile; also s within 16-tile for B)
    const int lk = (l >> 4) * 8;      // this lane's 8-elem k-offset within a 32-chunk

    const __hip_bfloat16* Ab = AT + (n0 + lr) * (long)LDAT + kb + lk;
    const __hip_bfloat16* Bb = WT + (long)lr * NN + kb + lk;

    bf16x8 af[2][4], bf[2][2];
    f32x4 acc[4][2];
#pragma unroll
    for (int mt = 0; mt < 4; ++mt)
#pragma unroll
        for (int sb = 0; sb < 2; ++sb) acc[mt][sb] = (f32x4){0.f, 0.f, 0.f, 0.f};

#pragma unroll
    for (int mt = 0; mt < 4; ++mt) af[0][mt] = *(const bf16x8*)(Ab + (long)mt * 16 * LDAT);
#pragma unroll
    for (int sb = 0; sb < 2; ++sb) bf[0][sb] = *(const bf16x8*)(Bb + (long)sb * 16 * NN);

#pragma unroll
    for (int kk = 0; kk < NKS; ++kk) {
        if (kk + 1 < NKS) {
#pragma unroll
            for (int mt = 0; mt < 4; ++mt)
                af[(kk + 1) & 1][mt] = *(const bf16x8*)(Ab + (long)mt * 16 * LDAT + (kk + 1) * 32);
#pragma unroll
            for (int sb = 0; sb < 2; ++sb)
                bf[(kk + 1) & 1][sb] = *(const bf16x8*)(Bb + (long)sb * 16 * NN + (kk + 1) * 32);
        }
#pragma unroll
        for (int mt = 0; mt < 4; ++mt)
#pragma unroll
            for (int sb = 0; sb < 2; ++sb)
                acc[mt][sb] = __builtin_amdgcn_mfma_f32_16x16x32_bf16(
                    af[kk & 1][mt], bf[kk & 1][sb], acc[mt][sb], 0, 0, 0);
    }

    // C/D layout: col = lane&15 (s), row = (lane>>4)*4 + reg (n)
    float* Pz = P + (long)blockIdx.y * PZSTRIDE;
#pragma unroll
    for (int mt = 0; mt < 4; ++mt)
#pragma unroll
        for (int sb = 0; sb < 2; ++sb)
#pragma unroll
            for (int r = 0; r < 4; ++r) {
                long n = n0 + mt * 16 + (l >> 4) * 4 + r;
                Pz[n * NSPEC + sb * 16 + lr] = acc[mt][sb][r];
            }
}

// ---------------- reduce split-K partials -> W f32 (8192x32) + WT bf16 (32x8192) -------------
__global__ void reduce_W(const float* __restrict__ P, float* __restrict__ Wf,
                         __hip_bfloat16* __restrict__ WTbf) {
    __shared__ float tile[64 * 33];
    int n0 = blockIdx.x * 64;
    int t = threadIdx.x;
    for (int i = 0; i < 8; ++i) {
        int idx = i * 256 + t;
        int r = idx >> 5, s = idx & 31;
        long off = (long)(n0 + r) * NSPEC + s;
        float v = 0.f;
#pragma unroll
        for (int z = 0; z < ZS; ++z) v += P[(long)z * PZSTRIDE + off];
        Wf[off] = v;
        tile[r * 33 + s] = v;
    }
    __syncthreads();
    for (int i = 0; i < 8; ++i) {
        int idx = i * 256 + t;
        int s = idx >> 6, r = idx & 63;
        WTbf[(long)s * NN + n0 + r] = __float2bfloat16(tile[r * 33 + s]);
    }
}

// ---------------- Phi[k,s,d] = sum_n W_k[n,s] * H[n,d]  (f32, atomic split over n) -----------
__global__ void phi_kernel(const float* __restrict__ W0, const float* __restrict__ W1,
                           const float* __restrict__ W2, const float* __restrict__ W3,
                           const float* __restrict__ H, float* __restrict__ Phi) {
    __shared__ float ldsW[64 * NSPEC];   // 8 KB
    int t = threadIdx.x;
    int s0 = (t >> 6) * 8;
    int d0 = (t & 63) * 4;
    int n0 = blockIdx.x * 128;
    int k = blockIdx.y;
    const float* W = (k == 0) ? W0 : (k == 1) ? W1 : (k == 2) ? W2 : W3;
    float4 acc[8];
#pragma unroll
    for (int j = 0; j < 8; ++j) acc[j] = (float4){0.f, 0.f, 0.f, 0.f};

    for (int tile = 0; tile < 2; ++tile) {
        int nb = n0 + tile * 64;
#pragma unroll
        for (int i = 0; i < 8; ++i) {
            int idx = i * 256 + t;
            ldsW[idx] = W[(long)(nb + (idx >> 5)) * NSPEC + (idx & 31)];
        }
        __syncthreads();
        for (int nn = 0; nn < 64; ++nn) {
            float4 x = *(const float4*)&H[(long)(nb + nn) * DIM + d0];
#pragma unroll
            for (int j = 0; j < 8; ++j) {
                float vs = ldsW[nn * NSPEC + s0 + j];
                acc[j].x += vs * x.x; acc[j].y += vs * x.y;
                acc[j].z += vs * x.z; acc[j].w += vs * x.w;
            }
        }
        __syncthreads();
    }
#pragma unroll
    for (int j = 0; j < 8; ++j) {
        float* ph = &Phi[((k * NSPEC) + s0 + j) * DIM + d0];
        atomicAdd(ph + 0, acc[j].x);
        atomicAdd(ph + 1, acc[j].y);
        atomicAdd(ph + 2, acc[j].z);
        atomicAdd(ph + 3, acc[j].w);
    }
}

// ---------------- Tc[s,d] = spec_w*sum_k hw*q - lap*eig*sum_k hw*phi; + tail outputs ---------
__global__ void tc_kernel(const float* __restrict__ Phi,
                          const float* __restrict__ eigvals,
                          const float* __restrict__ spec_logits,
                          const float* __restrict__ lap_logits,
                          const float* __restrict__ hop_weights,
                          float* __restrict__ Tc,
                          float* __restrict__ out_tail) {
    int s = blockIdx.x, t = threadIdx.x;
    float hw0 = hop_weights[0], hw1 = hop_weights[1], hw2 = hop_weights[2], hw3 = hop_weights[3];
    float hm = fmaxf(fmaxf(hw0, hw1), fmaxf(hw2, hw3));
    hw0 = expf(hw0 - hm); hw1 = expf(hw1 - hm); hw2 = expf(hw2 - hm); hw3 = expf(hw3 - hm);
    float hs = hw0 + hw1 + hw2 + hw3;
    hw0 /= hs; hw1 /= hs; hw2 /= hs; hw3 /= hs;
    float hw[4] = {hw0, hw1, hw2, hw3};
    float sm = -1e30f;
    for (int j = 0; j < NSPEC; ++j) sm = fmaxf(sm, spec_logits[j]);
    float ssum = 0.f;
    for (int j = 0; j < NSPEC; ++j) ssum += expf(spec_logits[j] - sm);
    float spec_w_s = expf(spec_logits[s] - sm) / ssum;
    float lp = lap_logits[s];
    float lap = (lp > 20.f) ? lp : log1pf(expf(lp));
    float le = lap * eigvals[s];

    __shared__ float red[4];
    float accR = 0.f, accL = 0.f;
    for (int k = 0; k < 4; ++k) {
        float phi = Phi[(k * NSPEC + s) * DIM + t];
        float v = phi * phi;
        for (int off = 32; off; off >>= 1) v += __shfl_xor(v, off);
        if ((t & 63) == 0) red[t >> 6] = v;
        __syncthreads();
        float ssq = red[0] + red[1] + red[2] + red[3];
        __syncthreads();
        float q = COEFF * phi / (1.f + COEFF * ssq);   // Sherman-Morrison: solve(I+c*pp^T, p)
        accR += hw[k] * q;
        accL += hw[k] * phi;
    }
    Tc[s * DIM + t] = spec_w_s * accR - le * accL;
    if (s == 0) {
        if (t < 4) out_tail[t] = hw[t];
        if (t < NSPEC) out_tail[4 + t] = expf(spec_logits[t] - sm) / ssum;
    }
}

// ---------------- final: G=V@Tc, H_half=H+ETA*G, soft-threshold, LayerNorm ----------------
__launch_bounds__(256)
__global__ void final_kernel(const float* __restrict__ H, const float* __restrict__ V,
                             const float* __restrict__ Tc, const float* __restrict__ thr,
                             const float* __restrict__ gamma, const float* __restrict__ beta,
                             float* __restrict__ out) {
    __shared__ float tc[NSPEC * DIM];   // 32 KB
    int t = threadIdx.x;
    {
        const float4* s4 = (const float4*)Tc;
        float4* d4 = (float4*)tc;
        for (int i = 0; i < 8; ++i) d4[i * 256 + t] = s4[i * 256 + t];
    }
    __syncthreads();
    int w = t >> 6, l = t & 63;
    long row = (long)blockIdx.x * 4 + w;
    int d0 = l * 4;
    const float* vrow = V + row * NSPEC;
    float4 G = {0.f, 0.f, 0.f, 0.f};
#pragma unroll 8
    for (int s = 0; s < NSPEC; ++s) {
        float vs = vrow[s];
        float4 c4 = *(const float4*)&tc[s * DIM + d0];
        G.x += vs * c4.x; G.y += vs * c4.y; G.z += vs * c4.z; G.w += vs * c4.w;
    }
    float4 h = *(const float4*)&H[row * DIM + d0];
    float4 th = *(const float4*)&thr[d0];
    float y[4];
    y[0] = h.x + ETA * G.x; y[1] = h.y + ETA * G.y;
    y[2] = h.z + ETA * G.z; y[3] = h.w + ETA * G.w;
    float tv[4] = {th.x, th.y, th.z, th.w};
    float s1 = 0.f, s2 = 0.f;
#pragma unroll
    for (int j = 0; j < 4; ++j) {
        float a = fabsf(y[j]) - tv[j];
        y[j] = (a > 0.f) ? copysignf(a, y[j]) : 0.f;
        s1 += y[j];
        s2 += y[j] * y[j];
    }
    for (int off = 32; off; off >>= 1) { s1 += __shfl_xor(s1, off); s2 += __shfl_xor(s2, off); }
    float mean = s1 * (1.f / DIM);
    float var = s2 * (1.f / DIM) - mean * mean;
    float inv = rsqrtf(var + LNEPS);
    float4 g4 = *(const float4*)&gamma[d0];
    float4 b4 = *(const float4*)&beta[d0];
    float4 o;
    o.x = (y[0] - mean) * inv * g4.x + b4.x;
    o.y = (y[1] - mean) * inv * g4.y + b4.y;
    o.z = (y[2] - mean) * inv * g4.z + b4.z;
    o.w = (y[3] - mean) * inv * g4.w + b4.w;
    *(float4*)&out[row * DIM + d0] = o;
}

extern "C" void kernel_launch(void* const* d_in, const int* in_sizes, int n_in,
                              void* d_out, int out_size, void* d_ws, size_t ws_size,
                              hipStream_t stream) {
    const float* H = (const float*)d_in[0];
    const float* A = (const float*)d_in[1];
    const float* V = (const float*)d_in[2];
    const float* eigvals = (const float*)d_in[3];
    const float* spec_logits = (const float*)d_in[4];
    const float* lap_logits = (const float*)d_in[5];
    const float* hop_weights = (const float*)d_in[6];
    const float* threshold = (const float*)d_in[7];
    const float* ln_gamma = (const float*)d_in[8];
    const float* ln_beta = (const float*)d_in[9];

    char* ws = (char*)d_ws;
    __hip_bfloat16* ATbf = (__hip_bfloat16*)ws;                      // 8192*8320*2 = 136,314,880
    float*          P    = (float*)(ws + 136314880);                 // ZS*PZSTRIDE*4 = 33,587,200
    __hip_bfloat16* VTbf = (__hip_bfloat16*)(ws + 169902080);        // 512 KB
    float* W1f = (float*)(ws + 170426368);                           // 1 MB
    float* W2f = (float*)(ws + 171474944);                           // 1 MB
    float* W3f = (float*)(ws + 172523520);                           // 1 MB
    __hip_bfloat16* W1T = (__hip_bfloat16*)(ws + 173572096);         // 512 KB
    __hip_bfloat16* W2T = (__hip_bfloat16*)(ws + 174096384);         // 512 KB
    __hip_bfloat16* W3T = (__hip_bfloat16*)(ws + 174620672);         // 512 KB (unused output)
    float* Phi = (float*)(ws + 175144960);                           // 128 KB
    float* Tc  = (float*)(ws + 175276032);                           // 32 KB
    float* out = (float*)d_out;

    hipMemsetAsync(Phi, 0, 4 * NSPEC * DIM * sizeof(float), stream);
    castT_A<<<dim3(128, 128), 256, 0, stream>>>(A, ATbf);
    trans_V<<<128, 256, 0, stream>>>(V, VTbf);

    gemm_mfma<<<dim3(32, ZS), 256, 0, stream>>>(ATbf, VTbf, P);
    reduce_W<<<128, 256, 0, stream>>>(P, W1f, W1T);
    gemm_mfma<<<dim3(32, ZS), 256, 0, stream>>>(ATbf, W1T, P);
    reduce_W<<<128, 256, 0, stream>>>(P, W2f, W2T);
    gemm_mfma<<<dim3(32, ZS), 256, 0, stream>>>(ATbf, W2T, P);
    reduce_W<<<128, 256, 0, stream>>>(P, W3f, W3T);

    phi_kernel<<<dim3(64, 4), 256, 0, stream>>>(V, W1f, W2f, W3f, H, Phi);
    tc_kernel<<<NSPEC, 256, 0, stream>>>(Phi, eigvals, spec_logits, lap_logits, hop_weights,
                                         Tc, out + (long)NN * DIM);
    final_kernel<<<2048, 256, 0, stream>>>(H, V, Tc, threshold, ln_gamma, ln_beta, out);
}